// Round 1
// baseline (1122.915 us; speedup 1.0000x reference)
//
#include <hip/hip_runtime.h>
#include <math.h>

// ASFF_2: N=8, C1=256, C2=512, H=64, W=64, low-res 32x32.
// Pipeline:
//  K1 gemm: kt1 = w_down(128x512) @ input2   [N,128,1024]
//  K2 conv3x3: kt2 = w_enc(36x128x3x3) * kt1 [N,36,1024]
//  K3 softmax -> mask [N,1024,9,4]  (mask[k][q] = softmax_k kt2[k*4+q])
//  K4 CARAFE apply -> hires [N,512,64,64]
//  K5 gemm: u = w_up(256x512) @ hires        [N,256,4096]
//  K6 attn weights + fused = in1*lw0 + u*lw1 [N,256,4096]
//  K7 implicit-GEMM conv3x3 (256x2304 @ 2304x4096) + BN + SiLU -> out

#define EPS 1e-5f

// ---------------- fp32 tiled GEMM + bias: C[n] = A(MxK) @ B[n](KxNp) + bias ----------------
// BM=BN=64, BK=16, 256 threads, 4x4 register tile.
__global__ __launch_bounds__(256) void gemm_bias_kernel(
    const float* __restrict__ A, const float* __restrict__ B,
    const float* __restrict__ bias, float* __restrict__ C,
    int M, int K, int Np, long strideB, long strideC)
{
    const int n = blockIdx.z;
    const float* Bn = B + (long)n * strideB;
    float* Cn = C + (long)n * strideC;
    __shared__ __align__(16) float As[16][68];   // [BK][BM+4] pad: 16B-aligned rows, 2-way-max bank alias
    __shared__ __align__(16) float Bs[16][64];
    const int tid = threadIdx.x;
    const int tcol = tid & 15;
    const int trow = tid >> 4;
    const int rowBase = blockIdx.y * 64;
    const int colBase = blockIdx.x * 64;
    float acc[4][4] = {};
    for (int k0 = 0; k0 < K; k0 += 16) {
#pragma unroll
        for (int i = 0; i < 4; ++i) {
            int idx = i * 256 + tid;
            int r = idx >> 4, cc = idx & 15;
            As[cc][r] = A[(long)(rowBase + r) * K + k0 + cc];
        }
#pragma unroll
        for (int i = 0; i < 4; ++i) {
            int idx = i * 256 + tid;
            int r = idx >> 6, cc = idx & 63;
            Bs[r][cc] = Bn[(long)(k0 + r) * Np + colBase + cc];
        }
        __syncthreads();
#pragma unroll
        for (int kk = 0; kk < 16; ++kk) {
            float4 a4 = *reinterpret_cast<const float4*>(&As[kk][trow * 4]);
            float4 b4 = *reinterpret_cast<const float4*>(&Bs[kk][tcol * 4]);
            float a[4] = {a4.x, a4.y, a4.z, a4.w};
            float b[4] = {b4.x, b4.y, b4.z, b4.w};
#pragma unroll
            for (int i = 0; i < 4; ++i)
#pragma unroll
                for (int j = 0; j < 4; ++j)
                    acc[i][j] += a[i] * b[j];
        }
        __syncthreads();
    }
#pragma unroll
    for (int i = 0; i < 4; ++i) {
        int row = rowBase + trow * 4 + i;
        float bv = bias[row];
        float4 o = make_float4(acc[i][0] + bv, acc[i][1] + bv, acc[i][2] + bv, acc[i][3] + bv);
        *reinterpret_cast<float4*>(&Cn[(long)row * Np + colBase + tcol * 4]) = o;
    }
}

// ---------------- K2: 3x3 conv 128->36 @ 32x32, pad 1, + bias ----------------
__global__ __launch_bounds__(256) void enc_conv_kernel(
    const float* __restrict__ kt1, const float* __restrict__ w_enc,
    const float* __restrict__ b_enc, float* __restrict__ kt2)
{
    int gid = blockIdx.x * 256 + threadIdx.x;   // N*36*1024
    int w = gid & 31;
    int h = (gid >> 5) & 31;
    int co = (gid >> 10) % 36;
    int n = gid / (1024 * 36);
    float acc = b_enc[co];
    const float* wbase = w_enc + co * (128 * 9);
    const float* ibase = kt1 + (long)n * 128 * 1024;
    for (int ci = 0; ci < 128; ++ci) {
        const float* ip = ibase + ci * 1024;
        const float* wp = wbase + ci * 9;
#pragma unroll
        for (int t = 0; t < 9; ++t) {
            int dh = t / 3 - 1, dw = t % 3 - 1;
            int hh = h + dh, ww = w + dw;
            if (hh >= 0 && hh < 32 && ww >= 0 && ww < 32)
                acc += ip[hh * 32 + ww] * wp[t];
        }
    }
    kt2[gid] = acc;
}

// ---------------- K3: per (n,p,q) softmax over k=9 of kt2[n][k*4+q][p] ----------------
__global__ __launch_bounds__(256) void mask_softmax_kernel(
    const float* __restrict__ kt2, float* __restrict__ mask)
{
    int gid = blockIdx.x * 256 + threadIdx.x;   // N*1024*4
    int q = gid & 3;
    int p = (gid >> 2) & 1023;
    int n = gid >> 12;
    float s[9];
    float mx = -1e30f;
#pragma unroll
    for (int k = 0; k < 9; ++k) {
        s[k] = kt2[(long)(n * 36 + k * 4 + q) * 1024 + p];
        mx = fmaxf(mx, s[k]);
    }
    float sum = 0.f;
#pragma unroll
    for (int k = 0; k < 9; ++k) { s[k] = expf(s[k] - mx); sum += s[k]; }
    float inv = 1.f / sum;
    float* mp = mask + (long)(n * 1024 + p) * 36 + q;
#pragma unroll
    for (int k = 0; k < 9; ++k) mp[k * 4] = s[k] * inv;
}

// ---------------- K4: CARAFE apply: hires[n,c,2h+r1,2w+r2] = sum_k in2patch[c,k]*mask[k,q] ----------------
__global__ __launch_bounds__(256) void carafe_kernel(
    const float* __restrict__ in2, const float* __restrict__ mask,
    float* __restrict__ hires)
{
    int bx = blockIdx.x;            // N*32*64 : (n, h, cgroup)
    int cg = bx & 63;
    int h = (bx >> 6) & 31;
    int n = bx >> 11;
    int tid = threadIdx.x;
    int w = tid & 31;
    int cl = tid >> 5;
    int c = cg * 8 + cl;
    __shared__ float mrow[32 * 37];  // stride 37: conflict-free lane access
    const float* mg = mask + (long)(n * 1024 + h * 32) * 36;
    for (int idx = tid; idx < 32 * 36; idx += 256) {
        int pw = idx / 36, j = idx - pw * 36;
        mrow[pw * 37 + j] = mg[idx];
    }
    __syncthreads();
    const float* ip = in2 + (long)(n * 512 + c) * 1024;
    float acc[4] = {0.f, 0.f, 0.f, 0.f};
#pragma unroll
    for (int k = 0; k < 9; ++k) {
        int dh = k / 3 - 1, dw = k % 3 - 1;
        int hh = h + dh, ww = w + dw;
        float val = (hh >= 0 && hh < 32 && ww >= 0 && ww < 32) ? ip[hh * 32 + ww] : 0.f;
#pragma unroll
        for (int q = 0; q < 4; ++q)
            acc[q] += val * mrow[w * 37 + k * 4 + q];
    }
    float* op = hires + (long)(n * 512 + c) * 4096;
#pragma unroll
    for (int q = 0; q < 4; ++q) {
        int r1 = q >> 1, r2 = q & 1;
        op[(2 * h + r1) * 64 + 2 * w + r2] = acc[q];
    }
}

// ---------------- K6: level weights (softmax over 2) + fused blend ----------------
__global__ __launch_bounds__(256) void fuse_kernel(
    const float* __restrict__ input1, const float* __restrict__ u,
    const float* __restrict__ w_l1, const float* __restrict__ bn_l1,
    const float* __restrict__ w_l2, const float* __restrict__ bn_l2,
    const float* __restrict__ w_wl, const float* __restrict__ b_wl,
    float* __restrict__ fused)
{
    int bx = blockIdx.x;            // 8 * 64
    int n = bx >> 6;
    int p0 = (bx & 63) * 64;
    int tid = threadIdx.x;
    int pos = tid & 63;
    int chunk = tid >> 6;           // 0..3, each covers 64 channels
    int p = p0 + pos;
    const float* i1 = input1 + (long)n * 256 * 4096;
    const float* i2 = u + (long)n * 256 * 4096;
    float s1[8] = {}, s2[8] = {};
    for (int ci = chunk * 64; ci < chunk * 64 + 64; ++ci) {
        float x1 = i1[(long)ci * 4096 + p];
        float x2 = i2[(long)ci * 4096 + p];
#pragma unroll
        for (int j = 0; j < 8; ++j) {
            s1[j] += w_l1[j * 256 + ci] * x1;
            s2[j] += w_l2[j * 256 + ci] * x2;
        }
    }
    __shared__ float red[4][64][16];
    __shared__ float lw0s[64];
#pragma unroll
    for (int j = 0; j < 8; ++j) { red[chunk][pos][j] = s1[j]; red[chunk][pos][8 + j] = s2[j]; }
    __syncthreads();
    if (tid < 64) {
        float v[16];
#pragma unroll
        for (int j = 0; j < 16; ++j)
            v[j] = red[0][tid][j] + red[1][tid][j] + red[2][tid][j] + red[3][tid][j];
        float z0 = b_wl[0], z1 = b_wl[1];
#pragma unroll
        for (int j = 0; j < 8; ++j) {
            float g = bn_l1[j], b = bn_l1[8 + j], m = bn_l1[16 + j], va = bn_l1[24 + j];
            float y = (v[j] - m) * (g * rsqrtf(va + EPS)) + b;
            float sv = y / (1.f + expf(-y));
            z0 += w_wl[j] * sv;
            z1 += w_wl[16 + j] * sv;
            g = bn_l2[j]; b = bn_l2[8 + j]; m = bn_l2[16 + j]; va = bn_l2[24 + j];
            y = (v[8 + j] - m) * (g * rsqrtf(va + EPS)) + b;
            sv = y / (1.f + expf(-y));
            z0 += w_wl[8 + j] * sv;
            z1 += w_wl[24 + j] * sv;
        }
        lw0s[tid] = 1.f / (1.f + expf(z1 - z0));   // softmax over 2
    }
    __syncthreads();
    float lw0 = lw0s[pos], lw1 = 1.f - lw0;
    for (int ci = chunk * 64; ci < chunk * 64 + 64; ++ci) {
        long idx = (long)ci * 4096 + p;
        fused[(long)n * 256 * 4096 + idx] = i1[idx] * lw0 + i2[idx] * lw1;
    }
}

// ---------------- K7: implicit-GEMM 3x3 conv 256->256 @64x64 pad1 + BN + SiLU ----------------
// A = w_conv [256][2304] (ci*9 + kh*3 + kw), B = im2col(fused). Block col = one image row h.
__global__ __launch_bounds__(256) void out_conv_kernel(
    const float* __restrict__ w_conv, const float* __restrict__ fused,
    const float* __restrict__ bn_conv, float* __restrict__ out)
{
    const int n = blockIdx.z;
    const int h = blockIdx.x;           // colBase = h*64, one image row per block-col
    const int rowBase = blockIdx.y * 64;
    const float* Bn = fused + (long)n * 256 * 4096;
    __shared__ __align__(16) float As[16][68];
    __shared__ __align__(16) float Bs[16][64];
    const int tid = threadIdx.x;
    const int tcol = tid & 15;
    const int trow = tid >> 4;
    float acc[4][4] = {};
    for (int k0 = 0; k0 < 2304; k0 += 16) {
#pragma unroll
        for (int i = 0; i < 4; ++i) {
            int idx = i * 256 + tid;
            int r = idx >> 4, cc = idx & 15;
            As[cc][r] = w_conv[(long)(rowBase + r) * 2304 + k0 + cc];
        }
#pragma unroll
        for (int i = 0; i < 4; ++i) {
            int idx = i * 256 + tid;
            int r = idx >> 6, cc = idx & 63;       // cc = w
            int k = k0 + r;
            int ci = k / 9, t = k - ci * 9;
            int dh = t / 3 - 1, dw = t - (t / 3) * 3 - 1;
            int hh = h + dh, ww = cc + dw;
            float v = 0.f;
            if (hh >= 0 && hh < 64 && ww >= 0 && ww < 64)
                v = Bn[(long)ci * 4096 + hh * 64 + ww];
            Bs[r][cc] = v;
        }
        __syncthreads();
#pragma unroll
        for (int kk = 0; kk < 16; ++kk) {
            float4 a4 = *reinterpret_cast<const float4*>(&As[kk][trow * 4]);
            float4 b4 = *reinterpret_cast<const float4*>(&Bs[kk][tcol * 4]);
            float a[4] = {a4.x, a4.y, a4.z, a4.w};
            float b[4] = {b4.x, b4.y, b4.z, b4.w};
#pragma unroll
            for (int i = 0; i < 4; ++i)
#pragma unroll
                for (int j = 0; j < 4; ++j)
                    acc[i][j] += a[i] * b[j];
        }
        __syncthreads();
    }
#pragma unroll
    for (int i = 0; i < 4; ++i) {
        int co = rowBase + trow * 4 + i;
        float g = bn_conv[co], b = bn_conv[256 + co], m = bn_conv[512 + co], va = bn_conv[768 + co];
        float scale = g * rsqrtf(va + EPS);
        float4 o;
#pragma unroll
        for (int j = 0; j < 4; ++j) {
            float y = (acc[i][j] - m) * scale + b;
            ((float*)&o)[j] = y / (1.f + expf(-y));
        }
        *reinterpret_cast<float4*>(&out[(long)(n * 256 + co) * 4096 + h * 64 + tcol * 4]) = o;
    }
}

extern "C" void kernel_launch(void* const* d_in, const int* in_sizes, int n_in,
                              void* d_out, int out_size, void* d_ws, size_t ws_size,
                              hipStream_t stream)
{
    const float* input1 = (const float*)d_in[0];
    const float* input2 = (const float*)d_in[1];
    const float* w_down = (const float*)d_in[2];
    const float* b_down = (const float*)d_in[3];
    const float* w_enc  = (const float*)d_in[4];
    const float* b_enc  = (const float*)d_in[5];
    const float* w_up   = (const float*)d_in[6];
    const float* b_up   = (const float*)d_in[7];
    const float* w_l1   = (const float*)d_in[8];
    const float* bn_l1  = (const float*)d_in[9];
    const float* w_l2   = (const float*)d_in[10];
    const float* bn_l2  = (const float*)d_in[11];
    const float* w_wl   = (const float*)d_in[12];
    const float* b_wl   = (const float*)d_in[13];
    const float* w_conv = (const float*)d_in[14];
    const float* bn_conv= (const float*)d_in[15];
    float* out = (float*)d_out;

    // workspace layout (floats); fused aliases hires (dead after K5). Total ~107 MB.
    float* ws    = (float*)d_ws;
    float* kt1   = ws;                    // 8*128*1024   = 1,048,576
    float* kt2   = kt1 + 1048576;         // 8*36*1024    =   294,912
    float* maskb = kt2 + 294912;          // 8*1024*36    =   294,912
    float* hires = maskb + 294912;        // 8*512*4096   = 16,777,216
    float* u     = hires + 16777216;      // 8*256*4096   =  8,388,608
    float* fused = hires;                 // alias

    // K1: kt1 = w_down @ input2 + b_down
    gemm_bias_kernel<<<dim3(16, 2, 8), 256, 0, stream>>>(
        w_down, input2, b_down, kt1, 128, 512, 1024, 512L * 1024, 128L * 1024);
    // K2: kt2 = conv3x3(kt1, w_enc) + b_enc
    enc_conv_kernel<<<dim3(1152), 256, 0, stream>>>(kt1, w_enc, b_enc, kt2);
    // K3: mask softmax
    mask_softmax_kernel<<<dim3(128), 256, 0, stream>>>(kt2, maskb);
    // K4: CARAFE apply -> hires
    carafe_kernel<<<dim3(16384), 256, 0, stream>>>(input2, maskb, hires);
    // K5: u = w_up @ hires + b_up
    gemm_bias_kernel<<<dim3(64, 4, 8), 256, 0, stream>>>(
        w_up, hires, b_up, u, 256, 512, 4096, 512L * 4096, 256L * 4096);
    // K6: fused blend
    fuse_kernel<<<dim3(512), 256, 0, stream>>>(
        input1, u, w_l1, bn_l1, w_l2, bn_l2, w_wl, b_wl, fused);
    // K7: final conv + BN + SiLU
    out_conv_kernel<<<dim3(64, 4, 8), 256, 0, stream>>>(w_conv, fused, bn_conv, out);
}

// Round 2
// 479.313 us; speedup vs baseline: 2.3428x; 2.3428x over previous
//
#include <hip/hip_runtime.h>
#include <math.h>

// ASFF_2: N=8, C1=256, C2=512, H=64, W=64, low-res 32x32.
//  K1 gemm fp32: kt1 = w_down(128x512) @ input2       [N,128,1024]
//  K2 conv3x3 fp32: kt2 = w_enc * kt1                 [N,36,1024]
//  K3 softmax -> mask [N,1024,36]
//  K4 CARAFE apply -> hires bf16 [ci][p]              [N,512,4096]
//  K4b transpose -> hiresT bf16 [p][ci]
//  K5 MFMA gemm: u = w_up @ hiresT + b_up (fp32 out)  [N,256,4096]
//  K6 attn weights + fused = in1*lw0 + u*lw1 (fp32)
//  K6b transpose-cast -> fusedT bf16 padded [(h+1)*66+(w+1)][ci]
//  K7 MFMA 9-tap shifted GEMM + BN + SiLU -> out

#define EPS 1e-5f
typedef unsigned short u16;
typedef __attribute__((ext_vector_type(8))) __bf16 bf16x8;
typedef __attribute__((ext_vector_type(4))) float f32x4;

__device__ inline u16 f2bf(float x) {
    union { float f; unsigned u; } v; v.f = x;
    unsigned r = v.u + 0x7FFF + ((v.u >> 16) & 1);
    return (u16)(r >> 16);
}

// ---------------- fp32 tiled GEMM + bias (K1 only now) ----------------
__global__ __launch_bounds__(256) void gemm_bias_kernel(
    const float* __restrict__ A, const float* __restrict__ B,
    const float* __restrict__ bias, float* __restrict__ C,
    int M, int K, int Np, long strideB, long strideC)
{
    const int n = blockIdx.z;
    const float* Bn = B + (long)n * strideB;
    float* Cn = C + (long)n * strideC;
    __shared__ __align__(16) float As[16][68];
    __shared__ __align__(16) float Bs[16][64];
    const int tid = threadIdx.x;
    const int tcol = tid & 15;
    const int trow = tid >> 4;
    const int rowBase = blockIdx.y * 64;
    const int colBase = blockIdx.x * 64;
    float acc[4][4] = {};
    for (int k0 = 0; k0 < K; k0 += 16) {
#pragma unroll
        for (int i = 0; i < 4; ++i) {
            int idx = i * 256 + tid;
            int r = idx >> 4, cc = idx & 15;
            As[cc][r] = A[(long)(rowBase + r) * K + k0 + cc];
        }
#pragma unroll
        for (int i = 0; i < 4; ++i) {
            int idx = i * 256 + tid;
            int r = idx >> 6, cc = idx & 63;
            Bs[r][cc] = Bn[(long)(k0 + r) * Np + colBase + cc];
        }
        __syncthreads();
#pragma unroll
        for (int kk = 0; kk < 16; ++kk) {
            float4 a4 = *reinterpret_cast<const float4*>(&As[kk][trow * 4]);
            float4 b4 = *reinterpret_cast<const float4*>(&Bs[kk][tcol * 4]);
            float a[4] = {a4.x, a4.y, a4.z, a4.w};
            float b[4] = {b4.x, b4.y, b4.z, b4.w};
#pragma unroll
            for (int i = 0; i < 4; ++i)
#pragma unroll
                for (int j = 0; j < 4; ++j)
                    acc[i][j] += a[i] * b[j];
        }
        __syncthreads();
    }
#pragma unroll
    for (int i = 0; i < 4; ++i) {
        int row = rowBase + trow * 4 + i;
        float bv = bias[row];
        float4 o = make_float4(acc[i][0] + bv, acc[i][1] + bv, acc[i][2] + bv, acc[i][3] + bv);
        *reinterpret_cast<float4*>(&Cn[(long)row * Np + colBase + tcol * 4]) = o;
    }
}

// ---------------- K2: 3x3 conv 128->36 @ 32x32, pad 1, + bias ----------------
__global__ __launch_bounds__(256) void enc_conv_kernel(
    const float* __restrict__ kt1, const float* __restrict__ w_enc,
    const float* __restrict__ b_enc, float* __restrict__ kt2)
{
    int gid = blockIdx.x * 256 + threadIdx.x;   // N*36*1024
    int w = gid & 31;
    int h = (gid >> 5) & 31;
    int co = (gid >> 10) % 36;
    int n = gid / (1024 * 36);
    float acc = b_enc[co];
    const float* wbase = w_enc + co * (128 * 9);
    const float* ibase = kt1 + (long)n * 128 * 1024;
    for (int ci = 0; ci < 128; ++ci) {
        const float* ip = ibase + ci * 1024;
        const float* wp = wbase + ci * 9;
#pragma unroll
        for (int t = 0; t < 9; ++t) {
            int dh = t / 3 - 1, dw = t % 3 - 1;
            int hh = h + dh, ww = w + dw;
            if (hh >= 0 && hh < 32 && ww >= 0 && ww < 32)
                acc += ip[hh * 32 + ww] * wp[t];
        }
    }
    kt2[gid] = acc;
}

// ---------------- K3: softmax over k=9 ----------------
__global__ __launch_bounds__(256) void mask_softmax_kernel(
    const float* __restrict__ kt2, float* __restrict__ mask)
{
    int gid = blockIdx.x * 256 + threadIdx.x;   // N*1024*4
    int q = gid & 3;
    int p = (gid >> 2) & 1023;
    int n = gid >> 12;
    float s[9];
    float mx = -1e30f;
#pragma unroll
    for (int k = 0; k < 9; ++k) {
        s[k] = kt2[(long)(n * 36 + k * 4 + q) * 1024 + p];
        mx = fmaxf(mx, s[k]);
    }
    float sum = 0.f;
#pragma unroll
    for (int k = 0; k < 9; ++k) { s[k] = expf(s[k] - mx); sum += s[k]; }
    float inv = 1.f / sum;
    float* mp = mask + (long)(n * 1024 + p) * 36 + q;
#pragma unroll
    for (int k = 0; k < 9; ++k) mp[k * 4] = s[k] * inv;
}

// ---------------- K4: CARAFE apply -> hires bf16 [ci][p] ----------------
__global__ __launch_bounds__(256) void carafe_kernel(
    const float* __restrict__ in2, const float* __restrict__ mask,
    u16* __restrict__ hires)
{
    int bx = blockIdx.x;            // N*32*64 : (n, h, cgroup)
    int cg = bx & 63;
    int h = (bx >> 6) & 31;
    int n = bx >> 11;
    int tid = threadIdx.x;
    int w = tid & 31;
    int cl = tid >> 5;
    int c = cg * 8 + cl;
    __shared__ float mrow[32 * 37];
    const float* mg = mask + (long)(n * 1024 + h * 32) * 36;
    for (int idx = tid; idx < 32 * 36; idx += 256) {
        int pw = idx / 36, j = idx - pw * 36;
        mrow[pw * 37 + j] = mg[idx];
    }
    __syncthreads();
    const float* ip = in2 + (long)(n * 512 + c) * 1024;
    float acc[4] = {0.f, 0.f, 0.f, 0.f};
#pragma unroll
    for (int k = 0; k < 9; ++k) {
        int dh = k / 3 - 1, dw = k % 3 - 1;
        int hh = h + dh, ww = w + dw;
        float val = (hh >= 0 && hh < 32 && ww >= 0 && ww < 32) ? ip[hh * 32 + ww] : 0.f;
#pragma unroll
        for (int q = 0; q < 4; ++q)
            acc[q] += val * mrow[w * 37 + k * 4 + q];
    }
    u16* op = hires + (long)(n * 512 + c) * 4096;
#pragma unroll
    for (int q = 0; q < 4; ++q) {
        int r1 = q >> 1, r2 = q & 1;
        op[(2 * h + r1) * 64 + 2 * w + r2] = f2bf(acc[q]);
    }
}

// ---------------- transpose/cast: src [C][4096] -> dst bf16 [row(p)][C] ----------------
template<int C, bool SRCF32, bool PAD>
__global__ __launch_bounds__(256) void transpose_cast_kernel(
    const void* __restrict__ srcv, u16* __restrict__ dst)
{
    constexpr int CP = C + 2;                 // CP/2 odd -> conflict-free phase-1 writes
    __shared__ u16 lds[32 * CP];
    const int n = blockIdx.y;
    const int p0 = blockIdx.x * 32;
    const int tid = threadIdx.x;
    {
        const int w = tid & 31;
        const int chunk = tid >> 5;           // 0..7
        const int c0 = chunk * (C / 8), c1 = c0 + C / 8;
        if (SRCF32) {
            const float* src = (const float*)srcv + (long)n * C * 4096 + p0 + w;
            for (int ci = c0; ci < c1; ++ci)
                lds[w * CP + ci] = f2bf(src[(long)ci * 4096]);
        } else {
            const u16* src = (const u16*)srcv + (long)n * C * 4096 + p0 + w;
            for (int ci = c0; ci < c1; ++ci)
                lds[w * CP + ci] = src[(long)ci * 4096];
        }
    }
    __syncthreads();
    const int px = tid >> 3;                  // 0..31
    const int q = tid & 7;
    long prow;
    if (PAD) {
        int p = p0 + px;
        prow = (long)((p >> 6) + 1) * 66 + (p & 63) + 1;
    } else {
        prow = p0 + px;
    }
    u16* drow = dst + (long)n * (PAD ? 4356L : 4096L) * C + prow * C;
    const u16* lrow = lds + px * CP;
#pragma unroll
    for (int j = 0; j < C / 16; ++j) {
        int off = j * 16 + q * 2;
        *(unsigned*)(drow + off) = *(const unsigned*)(lrow + off);
    }
}

// ---------------- MFMA shifted-GEMM: C[co][p] = sum_t sum_ci A[t][co][ci]*B[row(p)+shift_t][ci] ----------------
// M=256 fixed. 128x128 tile, 4 waves (2x2), wave tile 64x64 = 4x4 frags of 16x16x32.
__global__ __launch_bounds__(256) void mfma_conv_kernel(
    const u16* __restrict__ A,      // [NT][256][Kc] bf16
    const u16* __restrict__ B,      // per image [rows][Kc] bf16
    const float* __restrict__ scale, const float* __restrict__ shift,
    float* __restrict__ C, int Kc, int NT, int padded,
    long strideB, long strideC, int silu)
{
    const int n = blockIdx.z;
    const u16* Bn = B + (long)n * strideB;
    float* Cn = C + (long)n * strideC;
    const int tid = threadIdx.x;
    const int lane = tid & 63;
    const int wid = tid >> 6;
    const int mw = wid >> 1, nw = wid & 1;
    const int lr = lane & 15, lk = lane >> 4;
    const int rowBase = blockIdx.y * 128;
    const int colBase = blockIdx.x * 128;
    int aOff[4], bOff[4];
#pragma unroll
    for (int mf = 0; mf < 4; ++mf)
        aOff[mf] = (rowBase + mw * 64 + mf * 16 + lr) * Kc + lk * 8;
#pragma unroll
    for (int nf = 0; nf < 4; ++nf) {
        int col = colBase + nw * 64 + nf * 16 + lr;
        int pr = padded ? ((col >> 6) + 1) * 66 + (col & 63) + 1 : col;
        bOff[nf] = pr * Kc + lk * 8;
    }
    f32x4 acc[4][4] = {};
    for (int t = 0; t < NT; ++t) {
        const u16* At = A + (long)t * 256 * Kc;
        int btap = padded ? ((t / 3 - 1) * 66 + (t % 3 - 1)) * Kc : 0;
        for (int k0 = 0; k0 < Kc; k0 += 32) {
            bf16x8 af[4], bfr[4];
#pragma unroll
            for (int mf = 0; mf < 4; ++mf)
                af[mf] = *(const bf16x8*)(At + aOff[mf] + k0);
#pragma unroll
            for (int nf = 0; nf < 4; ++nf)
                bfr[nf] = *(const bf16x8*)(Bn + bOff[nf] + btap + k0);
#pragma unroll
            for (int mf = 0; mf < 4; ++mf)
#pragma unroll
                for (int nf = 0; nf < 4; ++nf)
                    acc[mf][nf] = __builtin_amdgcn_mfma_f32_16x16x32_bf16(
                        af[mf], bfr[nf], acc[mf][nf], 0, 0, 0);
        }
    }
#pragma unroll
    for (int mf = 0; mf < 4; ++mf) {
#pragma unroll
        for (int reg = 0; reg < 4; ++reg) {
            int co = rowBase + mw * 64 + mf * 16 + lk * 4 + reg;
            float sc = scale[co], sh = shift[co];
#pragma unroll
            for (int nf = 0; nf < 4; ++nf) {
                int col = colBase + nw * 64 + nf * 16 + lr;
                float y = acc[mf][nf][reg] * sc + sh;
                if (silu) y = y / (1.f + expf(-y));
                Cn[(long)co * 4096 + col] = y;
            }
        }
    }
}

// ---------------- K6: level weights (softmax over 2) + fused blend ----------------
__global__ __launch_bounds__(256) void fuse_kernel(
    const float* __restrict__ input1, const float* __restrict__ u,
    const float* __restrict__ w_l1, const float* __restrict__ bn_l1,
    const float* __restrict__ w_l2, const float* __restrict__ bn_l2,
    const float* __restrict__ w_wl, const float* __restrict__ b_wl,
    float* __restrict__ fused)
{
    int bx = blockIdx.x;            // 8 * 64
    int n = bx >> 6;
    int p0 = (bx & 63) * 64;
    int tid = threadIdx.x;
    int pos = tid & 63;
    int chunk = tid >> 6;
    int p = p0 + pos;
    const float* i1 = input1 + (long)n * 256 * 4096;
    const float* i2 = u + (long)n * 256 * 4096;
    float s1[8] = {}, s2[8] = {};
    for (int ci = chunk * 64; ci < chunk * 64 + 64; ++ci) {
        float x1 = i1[(long)ci * 4096 + p];
        float x2 = i2[(long)ci * 4096 + p];
#pragma unroll
        for (int j = 0; j < 8; ++j) {
            s1[j] += w_l1[j * 256 + ci] * x1;
            s2[j] += w_l2[j * 256 + ci] * x2;
        }
    }
    __shared__ float red[4][64][16];
    __shared__ float lw0s[64];
#pragma unroll
    for (int j = 0; j < 8; ++j) { red[chunk][pos][j] = s1[j]; red[chunk][pos][8 + j] = s2[j]; }
    __syncthreads();
    if (tid < 64) {
        float v[16];
#pragma unroll
        for (int j = 0; j < 16; ++j)
            v[j] = red[0][tid][j] + red[1][tid][j] + red[2][tid][j] + red[3][tid][j];
        float z0 = b_wl[0], z1 = b_wl[1];
#pragma unroll
        for (int j = 0; j < 8; ++j) {
            float g = bn_l1[j], b = bn_l1[8 + j], m = bn_l1[16 + j], va = bn_l1[24 + j];
            float y = (v[j] - m) * (g * rsqrtf(va + EPS)) + b;
            float sv = y / (1.f + expf(-y));
            z0 += w_wl[j] * sv;
            z1 += w_wl[16 + j] * sv;
            g = bn_l2[j]; b = bn_l2[8 + j]; m = bn_l2[16 + j]; va = bn_l2[24 + j];
            y = (v[8 + j] - m) * (g * rsqrtf(va + EPS)) + b;
            sv = y / (1.f + expf(-y));
            z0 += w_wl[8 + j] * sv;
            z1 += w_wl[24 + j] * sv;
        }
        lw0s[tid] = 1.f / (1.f + expf(z1 - z0));
    }
    __syncthreads();
    float lw0 = lw0s[pos], lw1 = 1.f - lw0;
    for (int ci = chunk * 64; ci < chunk * 64 + 64; ++ci) {
        long idx = (long)ci * 4096 + p;
        fused[(long)n * 256 * 4096 + idx] = i1[idx] * lw0 + i2[idx] * lw1;
    }
}

// ---------------- prep kernels ----------------
__global__ __launch_bounds__(256) void prep_w_kernel(
    const float* __restrict__ w_conv, const float* __restrict__ w_up,
    u16* __restrict__ wT, u16* __restrict__ wupT)
{
    int gid = blockIdx.x * 256 + threadIdx.x;
    if (gid < 589824) {             // wT[t][co][ci] = w_conv[co][ci][t]
        int t = gid >> 16;
        int co = (gid >> 8) & 255;
        int ci = gid & 255;
        wT[gid] = f2bf(w_conv[(co * 256 + ci) * 9 + t]);
    }
    if (gid < 131072) wupT[gid] = f2bf(w_up[gid]);
}

__global__ void prep_bn_kernel(const float* __restrict__ bn_conv,
                               const float* __restrict__ b_up, float* __restrict__ bnp)
{
    int i = threadIdx.x;            // 256
    float g = bn_conv[i], b = bn_conv[256 + i], m = bn_conv[512 + i], v = bn_conv[768 + i];
    float sc = g * rsqrtf(v + EPS);
    bnp[i] = sc;
    bnp[256 + i] = b - m * sc;
    bnp[512 + i] = 1.f;
    bnp[768 + i] = b_up[i];
}

extern "C" void kernel_launch(void* const* d_in, const int* in_sizes, int n_in,
                              void* d_out, int out_size, void* d_ws, size_t ws_size,
                              hipStream_t stream)
{
    const float* input1 = (const float*)d_in[0];
    const float* input2 = (const float*)d_in[1];
    const float* w_down = (const float*)d_in[2];
    const float* b_down = (const float*)d_in[3];
    const float* w_enc  = (const float*)d_in[4];
    const float* b_enc  = (const float*)d_in[5];
    const float* w_up   = (const float*)d_in[6];
    const float* b_up   = (const float*)d_in[7];
    const float* w_l1   = (const float*)d_in[8];
    const float* bn_l1  = (const float*)d_in[9];
    const float* w_l2   = (const float*)d_in[10];
    const float* bn_l2  = (const float*)d_in[11];
    const float* w_wl   = (const float*)d_in[12];
    const float* b_wl   = (const float*)d_in[13];
    const float* w_conv = (const float*)d_in[14];
    const float* bn_conv= (const float*)d_in[15];
    float* out = (float*)d_out;

    // workspace layout (float units). ~109 MB total.
    float* ws    = (float*)d_ws;
    float* kt1   = ws;                       // 1,048,576 f
    float* kt2   = kt1 + 1048576;            //   294,912 f
    float* maskb = kt2 + 294912;             //   294,912 f
    float* u     = maskb + 294912;           // 8,388,608 f
    float* hireb = u + 8388608;              // 8,388,608 f : hires bf16 [ci][p] ; alias fused fp32
    float* btb   = hireb + 8388608;          // 8,388,608 f : hiresT bf16 / fusedT bf16 (aliased)
    float* wTf   = btb + 8388608;            //   294,912 f : wT bf16
    float* wupTf = wTf + 294912;             //    65,536 f
    float* bnp   = wupTf + 65536;            //     1,024 f
    u16* hires_bf = (u16*)hireb;
    float* fused  = hireb;                   // fp32, after hires_bf dead
    u16* bt       = (u16*)btb;
    u16* wT       = (u16*)wTf;
    u16* wupT     = (u16*)wupTf;

    // prep (independent of data pipeline)
    prep_w_kernel<<<dim3(2304), 256, 0, stream>>>(w_conv, w_up, wT, wupT);
    prep_bn_kernel<<<dim3(1), 256, 0, stream>>>(bn_conv, b_up, bnp);

    // K1: kt1 = w_down @ input2 + b_down
    gemm_bias_kernel<<<dim3(16, 2, 8), 256, 0, stream>>>(
        w_down, input2, b_down, kt1, 128, 512, 1024, 512L * 1024, 128L * 1024);
    // K2
    enc_conv_kernel<<<dim3(1152), 256, 0, stream>>>(kt1, w_enc, b_enc, kt2);
    // K3
    mask_softmax_kernel<<<dim3(128), 256, 0, stream>>>(kt2, maskb);
    // K4: CARAFE -> hires bf16 [ci][p]
    carafe_kernel<<<dim3(16384), 256, 0, stream>>>(input2, maskb, hires_bf);
    // K4b: transpose -> hiresT bf16 [p][512]
    transpose_cast_kernel<512, false, false><<<dim3(128, 8), 256, 0, stream>>>(hires_bf, bt);
    // K5: u = w_up @ hiresT + b_up (MFMA)
    mfma_conv_kernel<<<dim3(32, 2, 8), 256, 0, stream>>>(
        wupT, bt, bnp + 512, bnp + 768, u, 512, 1, 0,
        4096L * 512, 256L * 4096, 0);
    // K6: fused blend (fp32, into hires alias)
    fuse_kernel<<<dim3(512), 256, 0, stream>>>(
        input1, u, w_l1, bn_l1, w_l2, bn_l2, w_wl, b_wl, fused);
    // zero fusedT (padded borders), then K6b transpose-cast
    hipMemsetAsync(bt, 0, 8L * 4356 * 256 * 2, stream);
    transpose_cast_kernel<256, true, true><<<dim3(128, 8), 256, 0, stream>>>(fused, bt);
    // K7: final conv (9-tap shifted MFMA GEMM) + BN + SiLU
    mfma_conv_kernel<<<dim3(32, 2, 8), 256, 0, stream>>>(
        wT, bt, bnp, bnp + 256, out, 256, 9, 1,
        4356L * 256, 256L * 4096, 1);
}

// Round 3
// 342.470 us; speedup vs baseline: 3.2789x; 1.3996x over previous
//
#include <hip/hip_runtime.h>
#include <math.h>

// ASFF_2: N=8, C1=256, C2=512, H=64, W=64, low-res 32x32.
//  K1 down_gemm: ktT = bf16T(w_down @ input2 + b_down)  [N,34*34,128] padded
//  K2 enc_mfma: kt2 = 9-tap shifted MFMA GEMM           [N,36,1024] fp32
//  K3 softmax -> mask [N,1024,36]
//  K4 CARAFE apply -> hires bf16 [ci][p]                [N,512,4096]
//  K4b transpose -> hiresT bf16 [p][ci]
//  K5 MFMA gemm: u = w_up @ hiresT + b_up (fp32 out)    [N,256,4096]
//  K6 attn weights + fused = in1*lw0 + u*lw1 (fp32)
//  K6b transpose-cast -> fusedT bf16 padded [(h+1)*66+(w+1)][ci]
//  K7 MFMA 9-tap shifted GEMM + BN + SiLU -> out

#define EPS 1e-5f
typedef unsigned short u16;
typedef __attribute__((ext_vector_type(8))) __bf16 bf16x8;
typedef __attribute__((ext_vector_type(4))) float f32x4;

__device__ inline u16 f2bf(float x) {
    union { float f; unsigned u; } v; v.f = x;
    unsigned r = v.u + 0x7FFF + ((v.u >> 16) & 1);
    return (u16)(r >> 16);
}

// ---------------- K1: fp32 tiled GEMM, bf16-transposed-padded output ----------------
// A = w_down [128][512], B = input2 [n][512][1024], out ktT[n][(h+1)*34+w+1][128] bf16.
__global__ __launch_bounds__(256) void down_gemm_kernel(
    const float* __restrict__ A, const float* __restrict__ B,
    const float* __restrict__ bias, u16* __restrict__ ktT)
{
    const int n = blockIdx.z;
    const float* Bn = B + (long)n * 512 * 1024;
    __shared__ __align__(16) float As[16][68];
    __shared__ __align__(16) float Bs[16][64];
    const int tid = threadIdx.x;
    const int tcol = tid & 15;
    const int trow = tid >> 4;
    const int rowBase = blockIdx.y * 64;
    const int colBase = blockIdx.x * 64;
    float acc[4][4] = {};
    for (int k0 = 0; k0 < 512; k0 += 16) {
#pragma unroll
        for (int i = 0; i < 4; ++i) {
            int idx = i * 256 + tid;
            int r = idx >> 4, cc = idx & 15;
            As[cc][r] = A[(long)(rowBase + r) * 512 + k0 + cc];
        }
#pragma unroll
        for (int i = 0; i < 4; ++i) {
            int idx = i * 256 + tid;
            int r = idx >> 6, cc = idx & 63;
            Bs[r][cc] = Bn[(long)(k0 + r) * 1024 + colBase + cc];
        }
        __syncthreads();
#pragma unroll
        for (int kk = 0; kk < 16; ++kk) {
            float4 a4 = *reinterpret_cast<const float4*>(&As[kk][trow * 4]);
            float4 b4 = *reinterpret_cast<const float4*>(&Bs[kk][tcol * 4]);
            float a[4] = {a4.x, a4.y, a4.z, a4.w};
            float b[4] = {b4.x, b4.y, b4.z, b4.w};
#pragma unroll
            for (int i = 0; i < 4; ++i)
#pragma unroll
                for (int j = 0; j < 4; ++j)
                    acc[i][j] += a[i] * b[j];
        }
        __syncthreads();
    }
    u16* Kn = ktT + (long)n * 1156 * 128;
#pragma unroll
    for (int i = 0; i < 4; ++i) {
        int ch = rowBase + trow * 4 + i;
        float bv = bias[ch];
#pragma unroll
        for (int j = 0; j < 4; ++j) {
            int p = colBase + tcol * 4 + j;
            int pr = ((p >> 5) + 1) * 34 + (p & 31) + 1;
            Kn[pr * 128 + ch] = f2bf(acc[i][j] + bv);
        }
    }
}

// ---------------- K2: encoder conv as 9-tap shifted MFMA GEMM ----------------
// A = wencT [9][64][128] bf16 (co padded to 64, zeros >=36), B = ktT, C = kt2 [n][36][1024] fp32.
__global__ __launch_bounds__(64) void enc_mfma_kernel(
    const u16* __restrict__ A, const u16* __restrict__ B,
    const float* __restrict__ bias, float* __restrict__ C)
{
    const int n = blockIdx.y;
    const int lane = threadIdx.x;
    const int lr = lane & 15, lk = lane >> 4;
    const int p = blockIdx.x * 16 + lr;
    const int pr = ((p >> 5) + 1) * 34 + (p & 31) + 1;
    const u16* Bn = B + (long)n * 1156 * 128;
    const int bOff = pr * 128 + lk * 8;
    f32x4 acc[3] = {};
    for (int t = 0; t < 9; ++t) {
        const u16* At = A + t * 8192;
        const int btap = ((t / 3 - 1) * 34 + (t % 3 - 1)) * 128;
#pragma unroll
        for (int k0 = 0; k0 < 128; k0 += 32) {
            bf16x8 bf = *(const bf16x8*)(Bn + bOff + btap + k0);
#pragma unroll
            for (int mf = 0; mf < 3; ++mf) {
                bf16x8 af = *(const bf16x8*)(At + (mf * 16 + lr) * 128 + lk * 8 + k0);
                acc[mf] = __builtin_amdgcn_mfma_f32_16x16x32_bf16(af, bf, acc[mf], 0, 0, 0);
            }
        }
    }
    float* Cn = C + (long)n * 36 * 1024;
#pragma unroll
    for (int mf = 0; mf < 3; ++mf)
#pragma unroll
        for (int reg = 0; reg < 4; ++reg) {
            int co = mf * 16 + lk * 4 + reg;
            if (co < 36)
                Cn[(long)co * 1024 + p] = acc[mf][reg] + bias[co];
        }
}

// ---------------- K3: softmax over k=9 ----------------
__global__ __launch_bounds__(256) void mask_softmax_kernel(
    const float* __restrict__ kt2, float* __restrict__ mask)
{
    int gid = blockIdx.x * 256 + threadIdx.x;   // N*1024*4
    int q = gid & 3;
    int p = (gid >> 2) & 1023;
    int n = gid >> 12;
    float s[9];
    float mx = -1e30f;
#pragma unroll
    for (int k = 0; k < 9; ++k) {
        s[k] = kt2[(long)(n * 36 + k * 4 + q) * 1024 + p];
        mx = fmaxf(mx, s[k]);
    }
    float sum = 0.f;
#pragma unroll
    for (int k = 0; k < 9; ++k) { s[k] = expf(s[k] - mx); sum += s[k]; }
    float inv = 1.f / sum;
    float* mp = mask + (long)(n * 1024 + p) * 36 + q;
#pragma unroll
    for (int k = 0; k < 9; ++k) mp[k * 4] = s[k] * inv;
}

// ---------------- K4: CARAFE apply -> hires bf16 [ci][p] ----------------
__global__ __launch_bounds__(256) void carafe_kernel(
    const float* __restrict__ in2, const float* __restrict__ mask,
    u16* __restrict__ hires)
{
    int bx = blockIdx.x;            // N*32*64 : (n, h, cgroup)
    int cg = bx & 63;
    int h = (bx >> 6) & 31;
    int n = bx >> 11;
    int tid = threadIdx.x;
    int w = tid & 31;
    int cl = tid >> 5;
    int c = cg * 8 + cl;
    __shared__ float mrow[32 * 37];
    const float* mg = mask + (long)(n * 1024 + h * 32) * 36;
    for (int idx = tid; idx < 32 * 36; idx += 256) {
        int pw = idx / 36, j = idx - pw * 36;
        mrow[pw * 37 + j] = mg[idx];
    }
    __syncthreads();
    const float* ip = in2 + (long)(n * 512 + c) * 1024;
    float acc[4] = {0.f, 0.f, 0.f, 0.f};
#pragma unroll
    for (int k = 0; k < 9; ++k) {
        int dh = k / 3 - 1, dw = k % 3 - 1;
        int hh = h + dh, ww = w + dw;
        float val = (hh >= 0 && hh < 32 && ww >= 0 && ww < 32) ? ip[hh * 32 + ww] : 0.f;
#pragma unroll
        for (int q = 0; q < 4; ++q)
            acc[q] += val * mrow[w * 37 + k * 4 + q];
    }
    u16* op = hires + (long)(n * 512 + c) * 4096;
#pragma unroll
    for (int q = 0; q < 4; ++q) {
        int r1 = q >> 1, r2 = q & 1;
        op[(2 * h + r1) * 64 + 2 * w + r2] = f2bf(acc[q]);
    }
}

// ---------------- transpose/cast: src [C][4096] -> dst bf16 [row(p)][C] ----------------
template<int C, bool SRCF32, bool PAD>
__global__ __launch_bounds__(256) void transpose_cast_kernel(
    const void* __restrict__ srcv, u16* __restrict__ dst)
{
    constexpr int CP = C + 2;
    __shared__ u16 lds[32 * CP];
    const int n = blockIdx.y;
    const int p0 = blockIdx.x * 32;
    const int tid = threadIdx.x;
    {
        const int w = tid & 31;
        const int chunk = tid >> 5;
        const int c0 = chunk * (C / 8), c1 = c0 + C / 8;
        if (SRCF32) {
            const float* src = (const float*)srcv + (long)n * C * 4096 + p0 + w;
            for (int ci = c0; ci < c1; ++ci)
                lds[w * CP + ci] = f2bf(src[(long)ci * 4096]);
        } else {
            const u16* src = (const u16*)srcv + (long)n * C * 4096 + p0 + w;
            for (int ci = c0; ci < c1; ++ci)
                lds[w * CP + ci] = src[(long)ci * 4096];
        }
    }
    __syncthreads();
    const int px = tid >> 3;
    const int q = tid & 7;
    long prow;
    if (PAD) {
        int p = p0 + px;
        prow = (long)((p >> 6) + 1) * 66 + (p & 63) + 1;
    } else {
        prow = p0 + px;
    }
    u16* drow = dst + (long)n * (PAD ? 4356L : 4096L) * C + prow * C;
    const u16* lrow = lds + px * CP;
#pragma unroll
    for (int j = 0; j < C / 16; ++j) {
        int off = j * 16 + q * 2;
        *(unsigned*)(drow + off) = *(const unsigned*)(lrow + off);
    }
}

// ---------------- MFMA shifted-GEMM (K5/K7) ----------------
__global__ __launch_bounds__(256) void mfma_conv_kernel(
    const u16* __restrict__ A,      // [NT][256][Kc] bf16
    const u16* __restrict__ B,      // per image [rows][Kc] bf16
    const float* __restrict__ scale, const float* __restrict__ shift,
    float* __restrict__ C, int Kc, int NT, int padded,
    long strideB, long strideC, int silu)
{
    const int n = blockIdx.z;
    const u16* Bn = B + (long)n * strideB;
    float* Cn = C + (long)n * strideC;
    const int tid = threadIdx.x;
    const int lane = tid & 63;
    const int wid = tid >> 6;
    const int mw = wid >> 1, nw = wid & 1;
    const int lr = lane & 15, lk = lane >> 4;
    const int rowBase = blockIdx.y * 128;
    const int colBase = blockIdx.x * 128;
    int aOff[4], bOff[4];
#pragma unroll
    for (int mf = 0; mf < 4; ++mf)
        aOff[mf] = (rowBase + mw * 64 + mf * 16 + lr) * Kc + lk * 8;
#pragma unroll
    for (int nf = 0; nf < 4; ++nf) {
        int col = colBase + nw * 64 + nf * 16 + lr;
        int pr = padded ? ((col >> 6) + 1) * 66 + (col & 63) + 1 : col;
        bOff[nf] = pr * Kc + lk * 8;
    }
    f32x4 acc[4][4] = {};
    for (int t = 0; t < NT; ++t) {
        const u16* At = A + (long)t * 256 * Kc;
        int btap = padded ? ((t / 3 - 1) * 66 + (t % 3 - 1)) * Kc : 0;
        for (int k0 = 0; k0 < Kc; k0 += 32) {
            bf16x8 af[4], bfr[4];
#pragma unroll
            for (int mf = 0; mf < 4; ++mf)
                af[mf] = *(const bf16x8*)(At + aOff[mf] + k0);
#pragma unroll
            for (int nf = 0; nf < 4; ++nf)
                bfr[nf] = *(const bf16x8*)(Bn + bOff[nf] + btap + k0);
#pragma unroll
            for (int mf = 0; mf < 4; ++mf)
#pragma unroll
                for (int nf = 0; nf < 4; ++nf)
                    acc[mf][nf] = __builtin_amdgcn_mfma_f32_16x16x32_bf16(
                        af[mf], bfr[nf], acc[mf][nf], 0, 0, 0);
        }
    }
#pragma unroll
    for (int mf = 0; mf < 4; ++mf) {
#pragma unroll
        for (int reg = 0; reg < 4; ++reg) {
            int co = rowBase + mw * 64 + mf * 16 + lk * 4 + reg;
            float sc = scale[co], sh = shift[co];
#pragma unroll
            for (int nf = 0; nf < 4; ++nf) {
                int col = colBase + nw * 64 + nf * 16 + lr;
                float y = acc[mf][nf][reg] * sc + sh;
                if (silu) y = y / (1.f + expf(-y));
                Cn[(long)co * 4096 + col] = y;
            }
        }
    }
}

// ---------------- K6: level weights (softmax over 2) + fused blend ----------------
__global__ __launch_bounds__(256) void fuse_kernel(
    const float* __restrict__ input1, const float* __restrict__ u,
    const float* __restrict__ w_l1, const float* __restrict__ bn_l1,
    const float* __restrict__ w_l2, const float* __restrict__ bn_l2,
    const float* __restrict__ w_wl, const float* __restrict__ b_wl,
    float* __restrict__ fused)
{
    int bx = blockIdx.x;            // 8 * 64
    int n = bx >> 6;
    int p0 = (bx & 63) * 64;
    int tid = threadIdx.x;
    int pos = tid & 63;
    int chunk = tid >> 6;
    int p = p0 + pos;
    const float* i1 = input1 + (long)n * 256 * 4096;
    const float* i2 = u + (long)n * 256 * 4096;
    float s1[8] = {}, s2[8] = {};
    for (int ci = chunk * 64; ci < chunk * 64 + 64; ++ci) {
        float x1 = i1[(long)ci * 4096 + p];
        float x2 = i2[(long)ci * 4096 + p];
#pragma unroll
        for (int j = 0; j < 8; ++j) {
            s1[j] += w_l1[j * 256 + ci] * x1;
            s2[j] += w_l2[j * 256 + ci] * x2;
        }
    }
    __shared__ float red[4][64][16];
    __shared__ float lw0s[64];
#pragma unroll
    for (int j = 0; j < 8; ++j) { red[chunk][pos][j] = s1[j]; red[chunk][pos][8 + j] = s2[j]; }
    __syncthreads();
    if (tid < 64) {
        float v[16];
#pragma unroll
        for (int j = 0; j < 16; ++j)
            v[j] = red[0][tid][j] + red[1][tid][j] + red[2][tid][j] + red[3][tid][j];
        float z0 = b_wl[0], z1 = b_wl[1];
#pragma unroll
        for (int j = 0; j < 8; ++j) {
            float g = bn_l1[j], b = bn_l1[8 + j], m = bn_l1[16 + j], va = bn_l1[24 + j];
            float y = (v[j] - m) * (g * rsqrtf(va + EPS)) + b;
            float sv = y / (1.f + expf(-y));
            z0 += w_wl[j] * sv;
            z1 += w_wl[16 + j] * sv;
            g = bn_l2[j]; b = bn_l2[8 + j]; m = bn_l2[16 + j]; va = bn_l2[24 + j];
            y = (v[8 + j] - m) * (g * rsqrtf(va + EPS)) + b;
            sv = y / (1.f + expf(-y));
            z0 += w_wl[8 + j] * sv;
            z1 += w_wl[24 + j] * sv;
        }
        lw0s[tid] = 1.f / (1.f + expf(z1 - z0));
    }
    __syncthreads();
    float lw0 = lw0s[pos], lw1 = 1.f - lw0;
    for (int ci = chunk * 64; ci < chunk * 64 + 64; ++ci) {
        long idx = (long)ci * 4096 + p;
        fused[(long)n * 256 * 4096 + idx] = i1[idx] * lw0 + i2[idx] * lw1;
    }
}

// ---------------- prep kernels ----------------
__global__ __launch_bounds__(256) void prep_w_kernel(
    const float* __restrict__ w_conv, const float* __restrict__ w_up,
    const float* __restrict__ w_enc,
    u16* __restrict__ wT, u16* __restrict__ wupT, u16* __restrict__ wencT)
{
    int gid = blockIdx.x * 256 + threadIdx.x;
    if (gid < 589824) {             // wT[t][co][ci] = w_conv[co][ci][t]
        int t = gid >> 16;
        int co = (gid >> 8) & 255;
        int ci = gid & 255;
        wT[gid] = f2bf(w_conv[(co * 256 + ci) * 9 + t]);
    }
    if (gid < 131072) wupT[gid] = f2bf(w_up[gid]);
    if (gid < 73728) {              // wencT[t][co<64][ci] (zeros co>=36)
        int t = gid >> 13;
        int co = (gid >> 7) & 63;
        int ci = gid & 127;
        wencT[gid] = (co < 36) ? f2bf(w_enc[(co * 128 + ci) * 9 + t]) : (u16)0;
    }
}

__global__ void prep_bn_kernel(const float* __restrict__ bn_conv,
                               const float* __restrict__ b_up, float* __restrict__ bnp)
{
    int i = threadIdx.x;            // 256
    float g = bn_conv[i], b = bn_conv[256 + i], m = bn_conv[512 + i], v = bn_conv[768 + i];
    float sc = g * rsqrtf(v + EPS);
    bnp[i] = sc;
    bnp[256 + i] = b - m * sc;
    bnp[512 + i] = 1.f;
    bnp[768 + i] = b_up[i];
}

extern "C" void kernel_launch(void* const* d_in, const int* in_sizes, int n_in,
                              void* d_out, int out_size, void* d_ws, size_t ws_size,
                              hipStream_t stream)
{
    const float* input1 = (const float*)d_in[0];
    const float* input2 = (const float*)d_in[1];
    const float* w_down = (const float*)d_in[2];
    const float* b_down = (const float*)d_in[3];
    const float* w_enc  = (const float*)d_in[4];
    const float* b_enc  = (const float*)d_in[5];
    const float* w_up   = (const float*)d_in[6];
    const float* b_up   = (const float*)d_in[7];
    const float* w_l1   = (const float*)d_in[8];
    const float* bn_l1  = (const float*)d_in[9];
    const float* w_l2   = (const float*)d_in[10];
    const float* bn_l2  = (const float*)d_in[11];
    const float* w_wl   = (const float*)d_in[12];
    const float* b_wl   = (const float*)d_in[13];
    const float* w_conv = (const float*)d_in[14];
    const float* bn_conv= (const float*)d_in[15];
    float* out = (float*)d_out;

    // workspace layout (float units). ~108 MB total.
    float* ws     = (float*)d_ws;
    float* ktTf   = ws;                      //   591,872 f : ktT bf16 [n][1156][128]
    float* wencTf = ktTf + 591872;           //    36,864 f : wencT bf16 [9][64][128]
    float* kt2    = wencTf + 36864;          //   294,912 f
    float* maskb  = kt2 + 294912;            //   294,912 f
    float* u      = maskb + 294912;          // 8,388,608 f
    float* hireb  = u + 8388608;             // 8,388,608 f : hires bf16 [ci][p] ; alias fused fp32
    float* btb    = hireb + 8388608;         // 8,388,608 f : hiresT / fusedT bf16
    float* wTf    = btb + 8388608;           //   294,912 f
    float* wupTf  = wTf + 294912;            //    65,536 f
    float* bnp    = wupTf + 65536;           //     1,024 f
    u16* ktT      = (u16*)ktTf;
    u16* wencT    = (u16*)wencTf;
    u16* hires_bf = (u16*)hireb;
    float* fused  = hireb;
    u16* bt       = (u16*)btb;
    u16* wT       = (u16*)wTf;
    u16* wupT     = (u16*)wupTf;

    // prep (independent of data pipeline)
    prep_w_kernel<<<dim3(2304), 256, 0, stream>>>(w_conv, w_up, w_enc, wT, wupT, wencT);
    prep_bn_kernel<<<dim3(1), 256, 0, stream>>>(bn_conv, b_up, bnp);

    // K1: ktT = bf16T(w_down @ input2 + b_down), padded 34x34 grid
    hipMemsetAsync(ktT, 0, 8L * 1156 * 128 * 2, stream);
    down_gemm_kernel<<<dim3(16, 2, 8), 256, 0, stream>>>(w_down, input2, b_down, ktT);
    // K2: kt2 = 9-tap shifted MFMA GEMM
    enc_mfma_kernel<<<dim3(64, 8), 64, 0, stream>>>(wencT, ktT, b_enc, kt2);
    // K3
    mask_softmax_kernel<<<dim3(128), 256, 0, stream>>>(kt2, maskb);
    // K4: CARAFE -> hires bf16 [ci][p]
    carafe_kernel<<<dim3(16384), 256, 0, stream>>>(input2, maskb, hires_bf);
    // K4b: transpose -> hiresT bf16 [p][512]
    transpose_cast_kernel<512, false, false><<<dim3(128, 8), 256, 0, stream>>>(hires_bf, bt);
    // K5: u = w_up @ hiresT + b_up (MFMA)
    mfma_conv_kernel<<<dim3(32, 2, 8), 256, 0, stream>>>(
        wupT, bt, bnp + 512, bnp + 768, u, 512, 1, 0,
        4096L * 512, 256L * 4096, 0);
    // K6: fused blend (fp32, into hires alias)
    fuse_kernel<<<dim3(512), 256, 0, stream>>>(
        input1, u, w_l1, bn_l1, w_l2, bn_l2, w_wl, b_wl, fused);
    // zero fusedT (padded borders), then K6b transpose-cast
    hipMemsetAsync(bt, 0, 8L * 4356 * 256 * 2, stream);
    transpose_cast_kernel<256, true, true><<<dim3(128, 8), 256, 0, stream>>>(fused, bt);
    // K7: final conv (9-tap shifted MFMA GEMM) + BN + SiLU
    mfma_conv_kernel<<<dim3(32, 2, 8), 256, 0, stream>>>(
        wT, bt, bnp, bnp + 256, out, 256, 9, 1,
        4356L * 256, 256L * 4096, 1);
}

// Round 4
// 263.259 us; speedup vs baseline: 4.2654x; 1.3009x over previous
//
#include <hip/hip_runtime.h>
#include <math.h>

// ASFF_2: N=8, C1=256, C2=512, H=64, W=64, low-res 32x32.
//  K1 down_gemm: ktT = bf16T(w_down @ input2 + b_down)  [N,34*34,128] padded
//  K2 enc_mfma: kt2 = 9-tap shifted MFMA GEMM           [N,36,1024] fp32
//  K3 softmax -> mask [N,1024,36]
//  K4 CARAFE apply -> hires bf16 [ci][p]                [N,512,4096]
//  K4b transpose -> hiresT bf16 [p][ci]
//  K5 LDS-staged MFMA gemm: u = w_up @ hiresT + b_up    [N,256,4096]
//  K6 attn weights + fused = in1*lw0 + u*lw1 (fp32)
//  K6b transpose-cast -> fusedT bf16 padded [66x66 grid][ci]
//  K7 LDS-staged 9-tap MFMA conv + BN + SiLU -> out

#define EPS 1e-5f
typedef unsigned short u16;
typedef __attribute__((ext_vector_type(8))) __bf16 bf16x8;
typedef __attribute__((ext_vector_type(4))) float f32x4;

__device__ inline u16 f2bf(float x) {
    union { float f; unsigned u; } v; v.f = x;
    unsigned r = v.u + 0x7FFF + ((v.u >> 16) & 1);
    return (u16)(r >> 16);
}

// ---------------- K1: fp32 tiled GEMM, bf16-transposed-padded output ----------------
__global__ __launch_bounds__(256) void down_gemm_kernel(
    const float* __restrict__ A, const float* __restrict__ B,
    const float* __restrict__ bias, u16* __restrict__ ktT)
{
    const int n = blockIdx.z;
    const float* Bn = B + (long)n * 512 * 1024;
    __shared__ __align__(16) float As[16][68];
    __shared__ __align__(16) float Bs[16][64];
    const int tid = threadIdx.x;
    const int tcol = tid & 15;
    const int trow = tid >> 4;
    const int rowBase = blockIdx.y * 64;
    const int colBase = blockIdx.x * 64;
    float acc[4][4] = {};
    for (int k0 = 0; k0 < 512; k0 += 16) {
#pragma unroll
        for (int i = 0; i < 4; ++i) {
            int idx = i * 256 + tid;
            int r = idx >> 4, cc = idx & 15;
            As[cc][r] = A[(long)(rowBase + r) * 512 + k0 + cc];
        }
#pragma unroll
        for (int i = 0; i < 4; ++i) {
            int idx = i * 256 + tid;
            int r = idx >> 6, cc = idx & 63;
            Bs[r][cc] = Bn[(long)(k0 + r) * 1024 + colBase + cc];
        }
        __syncthreads();
#pragma unroll
        for (int kk = 0; kk < 16; ++kk) {
            float4 a4 = *reinterpret_cast<const float4*>(&As[kk][trow * 4]);
            float4 b4 = *reinterpret_cast<const float4*>(&Bs[kk][tcol * 4]);
            float a[4] = {a4.x, a4.y, a4.z, a4.w};
            float b[4] = {b4.x, b4.y, b4.z, b4.w};
#pragma unroll
            for (int i = 0; i < 4; ++i)
#pragma unroll
                for (int j = 0; j < 4; ++j)
                    acc[i][j] += a[i] * b[j];
        }
        __syncthreads();
    }
    u16* Kn = ktT + (long)n * 1156 * 128;
#pragma unroll
    for (int i = 0; i < 4; ++i) {
        int ch = rowBase + trow * 4 + i;
        float bv = bias[ch];
#pragma unroll
        for (int j = 0; j < 4; ++j) {
            int p = colBase + tcol * 4 + j;
            int pr = ((p >> 5) + 1) * 34 + (p & 31) + 1;
            Kn[pr * 128 + ch] = f2bf(acc[i][j] + bv);
        }
    }
}

// ---------------- K2: encoder conv as 9-tap shifted MFMA GEMM ----------------
__global__ __launch_bounds__(64) void enc_mfma_kernel(
    const u16* __restrict__ A, const u16* __restrict__ B,
    const float* __restrict__ bias, float* __restrict__ C)
{
    const int n = blockIdx.y;
    const int lane = threadIdx.x;
    const int lr = lane & 15, lk = lane >> 4;
    const int p = blockIdx.x * 16 + lr;
    const int pr = ((p >> 5) + 1) * 34 + (p & 31) + 1;
    const u16* Bn = B + (long)n * 1156 * 128;
    const int bOff = pr * 128 + lk * 8;
    f32x4 acc[3] = {};
    for (int t = 0; t < 9; ++t) {
        const u16* At = A + t * 8192;
        const int btap = ((t / 3 - 1) * 34 + (t % 3 - 1)) * 128;
#pragma unroll
        for (int k0 = 0; k0 < 128; k0 += 32) {
            bf16x8 bf = *(const bf16x8*)(Bn + bOff + btap + k0);
#pragma unroll
            for (int mf = 0; mf < 3; ++mf) {
                bf16x8 af = *(const bf16x8*)(At + (mf * 16 + lr) * 128 + lk * 8 + k0);
                acc[mf] = __builtin_amdgcn_mfma_f32_16x16x32_bf16(af, bf, acc[mf], 0, 0, 0);
            }
        }
    }
    float* Cn = C + (long)n * 36 * 1024;
#pragma unroll
    for (int mf = 0; mf < 3; ++mf)
#pragma unroll
        for (int reg = 0; reg < 4; ++reg) {
            int co = mf * 16 + lk * 4 + reg;
            if (co < 36)
                Cn[(long)co * 1024 + p] = acc[mf][reg] + bias[co];
        }
}

// ---------------- K3: softmax over k=9 ----------------
__global__ __launch_bounds__(256) void mask_softmax_kernel(
    const float* __restrict__ kt2, float* __restrict__ mask)
{
    int gid = blockIdx.x * 256 + threadIdx.x;   // N*1024*4
    int q = gid & 3;
    int p = (gid >> 2) & 1023;
    int n = gid >> 12;
    float s[9];
    float mx = -1e30f;
#pragma unroll
    for (int k = 0; k < 9; ++k) {
        s[k] = kt2[(long)(n * 36 + k * 4 + q) * 1024 + p];
        mx = fmaxf(mx, s[k]);
    }
    float sum = 0.f;
#pragma unroll
    for (int k = 0; k < 9; ++k) { s[k] = expf(s[k] - mx); sum += s[k]; }
    float inv = 1.f / sum;
    float* mp = mask + (long)(n * 1024 + p) * 36 + q;
#pragma unroll
    for (int k = 0; k < 9; ++k) mp[k * 4] = s[k] * inv;
}

// ---------------- K4: CARAFE apply -> hires bf16 [ci][p] ----------------
__global__ __launch_bounds__(256) void carafe_kernel(
    const float* __restrict__ in2, const float* __restrict__ mask,
    u16* __restrict__ hires)
{
    int bx = blockIdx.x;            // N*32*64 : (n, h, cgroup)
    int cg = bx & 63;
    int h = (bx >> 6) & 31;
    int n = bx >> 11;
    int tid = threadIdx.x;
    int w = tid & 31;
    int cl = tid >> 5;
    int c = cg * 8 + cl;
    __shared__ float mrow[32 * 37];
    const float* mg = mask + (long)(n * 1024 + h * 32) * 36;
    for (int idx = tid; idx < 32 * 36; idx += 256) {
        int pw = idx / 36, j = idx - pw * 36;
        mrow[pw * 37 + j] = mg[idx];
    }
    __syncthreads();
    const float* ip = in2 + (long)(n * 512 + c) * 1024;
    float acc[4] = {0.f, 0.f, 0.f, 0.f};
#pragma unroll
    for (int k = 0; k < 9; ++k) {
        int dh = k / 3 - 1, dw = k % 3 - 1;
        int hh = h + dh, ww = w + dw;
        float val = (hh >= 0 && hh < 32 && ww >= 0 && ww < 32) ? ip[hh * 32 + ww] : 0.f;
#pragma unroll
        for (int q = 0; q < 4; ++q)
            acc[q] += val * mrow[w * 37 + k * 4 + q];
    }
    u16* op = hires + (long)(n * 512 + c) * 4096;
#pragma unroll
    for (int q = 0; q < 4; ++q) {
        int r1 = q >> 1, r2 = q & 1;
        op[(2 * h + r1) * 64 + 2 * w + r2] = f2bf(acc[q]);
    }
}

// ---------------- transpose/cast: src [C][4096] -> dst bf16 [row(p)][C] ----------------
template<int C, bool SRCF32, bool PAD>
__global__ __launch_bounds__(256) void transpose_cast_kernel(
    const void* __restrict__ srcv, u16* __restrict__ dst)
{
    constexpr int CP = C + 2;
    __shared__ u16 lds[32 * CP];
    const int n = blockIdx.y;
    const int p0 = blockIdx.x * 32;
    const int tid = threadIdx.x;
    {
        const int w = tid & 31;
        const int chunk = tid >> 5;
        const int c0 = chunk * (C / 8), c1 = c0 + C / 8;
        if (SRCF32) {
            const float* src = (const float*)srcv + (long)n * C * 4096 + p0 + w;
            for (int ci = c0; ci < c1; ++ci)
                lds[w * CP + ci] = f2bf(src[(long)ci * 4096]);
        } else {
            const u16* src = (const u16*)srcv + (long)n * C * 4096 + p0 + w;
            for (int ci = c0; ci < c1; ++ci)
                lds[w * CP + ci] = src[(long)ci * 4096];
        }
    }
    __syncthreads();
    const int px = tid >> 3;
    const int q = tid & 7;
    long prow;
    if (PAD) {
        int p = p0 + px;
        prow = (long)((p >> 6) + 1) * 66 + (p & 63) + 1;
    } else {
        prow = p0 + px;
    }
    u16* drow = dst + (long)n * (PAD ? 4356L : 4096L) * C + prow * C;
    const u16* lrow = lds + px * CP;
#pragma unroll
    for (int j = 0; j < C / 16; ++j) {
        int off = j * 16 + q * 2;
        *(unsigned*)(drow + off) = *(const unsigned*)(lrow + off);
    }
}

// ---------------- K5/K7: LDS-staged MFMA shifted-GEMM ----------------
// B staged per 32-ci step via global_load_lds(16B), double-buffered; region covers
// all NT taps (4 padded image rows x 66 for PADDED). XOR bank-swizzle applied via
// pre-swizzled global source (LDS dest must stay linear), inverse on ds_read.
#define STAGE(bufi, k0s)                                                              \
    for (int i = wid; i < NLOAD; i += 4) {                                            \
        int f = i * 64 + lane;                                                        \
        int r = f >> 2;                                                               \
        int p16 = (f & 3) ^ ((r >> 2) & 3);                                           \
        const u16* gsrc = Bn + (long)(g0 + r) * KC + (k0s) + p16 * 8;                 \
        __builtin_amdgcn_global_load_lds(                                             \
            (const __attribute__((address_space(1))) void*)gsrc,                      \
            (__attribute__((address_space(3))) void*)(lds + (bufi) * BUFU + i * 512), \
            16, 0, 0);                                                                \
    }

template<int KC, int NT, bool PADDED>
__global__ __launch_bounds__(256, 2) void mfma_conv_lds_kernel(
    const u16* __restrict__ A,      // [NT][256][KC] bf16
    const u16* __restrict__ B,      // per image [rows][KC] bf16
    const float* __restrict__ scale, const float* __restrict__ shift,
    float* __restrict__ C, long strideB, long strideC, int silu)
{
    constexpr int RROWS = PADDED ? 272 : 128;   // 264 real + 8 overshoot (never read)
    constexpr int NLOAD = RROWS * 4 / 64;       // 17 : 8 global_load_lds per buffer
    constexpr int BUFU  = RROWS * 32;           // u16 per buffer
    __shared__ __align__(16) u16 lds[2 * BUFU];
    const int n = blockIdx.z;
    const u16* Bn = B + (long)n * strideB;
    float* Cn = C + (long)n * strideC;
    const int tid = threadIdx.x;
    const int lane = tid & 63;
    const int wid = tid >> 6;
    const int mw = wid >> 1, nw = wid & 1;
    const int lr = lane & 15, lk = lane >> 4;
    const int rowBase = blockIdx.y * 128;
    const int colBase = blockIdx.x * 128;
    const int g0 = PADDED ? (colBase >> 6) * 66 : colBase;

    long aBase[4];
#pragma unroll
    for (int mf = 0; mf < 4; ++mf)
        aBase[mf] = (long)(rowBase + mw * 64 + mf * 16 + lr) * KC + lk * 8;

    f32x4 acc[4][4] = {};
    bf16x8 af[4], afn[4];
#pragma unroll
    for (int mf = 0; mf < 4; ++mf)
        af[mf] = *(const bf16x8*)(A + aBase[mf]);       // (t=0, k0=0)
    STAGE(0, 0);

    constexpr int NK = KC / 32;
    int cur = 0;
    for (int kx = 0; kx < NK; ++kx) {
        __syncthreads();                                 // drains staging of lds[cur]
        if (kx + 1 < NK) { STAGE(cur ^ 1, (kx + 1) * 32); }
#pragma unroll
        for (int t = 0; t < NT; ++t) {
            // prefetch A for next tap (or next k0's tap 0)
            int tn = (t + 1 == NT) ? 0 : t + 1;
            int kn = (t + 1 == NT) ? ((kx + 1 < NK) ? (kx + 1) * 32 : 0) : kx * 32;
            const u16* An = A + (long)tn * 256 * KC + kn;
#pragma unroll
            for (int mf = 0; mf < 4; ++mf)
                afn[mf] = *(const bf16x8*)(An + aBase[mf]);
            int rb;
            if (PADDED) {
                int dh = t / 3 - 1, dw = t % 3 - 1;
                rb = (nw + dh + 1) * 66 + dw + 1 + lr;
            } else {
                rb = nw * 64 + lr;
            }
            bf16x8 bfr[4];
#pragma unroll
            for (int nf = 0; nf < 4; ++nf) {
                int r = rb + nf * 16;
                bfr[nf] = *(const bf16x8*)(lds + cur * BUFU + r * 32 + (lk ^ ((r >> 2) & 3)) * 8);
            }
#pragma unroll
            for (int mf = 0; mf < 4; ++mf)
#pragma unroll
                for (int nf = 0; nf < 4; ++nf)
                    acc[mf][nf] = __builtin_amdgcn_mfma_f32_16x16x32_bf16(
                        af[mf], bfr[nf], acc[mf][nf], 0, 0, 0);
#pragma unroll
            for (int mf = 0; mf < 4; ++mf) af[mf] = afn[mf];
        }
        cur ^= 1;
    }
#pragma unroll
    for (int mf = 0; mf < 4; ++mf) {
#pragma unroll
        for (int reg = 0; reg < 4; ++reg) {
            int co = rowBase + mw * 64 + mf * 16 + lk * 4 + reg;
            float sc = scale[co], sh = shift[co];
#pragma unroll
            for (int nf = 0; nf < 4; ++nf) {
                int col = colBase + nw * 64 + nf * 16 + lr;
                float y = acc[mf][nf][reg] * sc + sh;
                if (silu) y = y / (1.f + expf(-y));
                Cn[(long)co * 4096 + col] = y;
            }
        }
    }
}

// ---------------- K6: level weights (softmax over 2) + fused blend ----------------
__global__ __launch_bounds__(256) void fuse_kernel(
    const float* __restrict__ input1, const float* __restrict__ u,
    const float* __restrict__ w_l1, const float* __restrict__ bn_l1,
    const float* __restrict__ w_l2, const float* __restrict__ bn_l2,
    const float* __restrict__ w_wl, const float* __restrict__ b_wl,
    float* __restrict__ fused)
{
    int bx = blockIdx.x;            // 8 * 64
    int n = bx >> 6;
    int p0 = (bx & 63) * 64;
    int tid = threadIdx.x;
    int pos = tid & 63;
    int chunk = tid >> 6;
    int p = p0 + pos;
    const float* i1 = input1 + (long)n * 256 * 4096;
    const float* i2 = u + (long)n * 256 * 4096;
    float s1[8] = {}, s2[8] = {};
    for (int ci = chunk * 64; ci < chunk * 64 + 64; ++ci) {
        float x1 = i1[(long)ci * 4096 + p];
        float x2 = i2[(long)ci * 4096 + p];
#pragma unroll
        for (int j = 0; j < 8; ++j) {
            s1[j] += w_l1[j * 256 + ci] * x1;
            s2[j] += w_l2[j * 256 + ci] * x2;
        }
    }
    __shared__ float red[4][64][16];
    __shared__ float lw0s[64];
#pragma unroll
    for (int j = 0; j < 8; ++j) { red[chunk][pos][j] = s1[j]; red[chunk][pos][8 + j] = s2[j]; }
    __syncthreads();
    if (tid < 64) {
        float v[16];
#pragma unroll
        for (int j = 0; j < 16; ++j)
            v[j] = red[0][tid][j] + red[1][tid][j] + red[2][tid][j] + red[3][tid][j];
        float z0 = b_wl[0], z1 = b_wl[1];
#pragma unroll
        for (int j = 0; j < 8; ++j) {
            float g = bn_l1[j], b = bn_l1[8 + j], m = bn_l1[16 + j], va = bn_l1[24 + j];
            float y = (v[j] - m) * (g * rsqrtf(va + EPS)) + b;
            float sv = y / (1.f + expf(-y));
            z0 += w_wl[j] * sv;
            z1 += w_wl[16 + j] * sv;
            g = bn_l2[j]; b = bn_l2[8 + j]; m = bn_l2[16 + j]; va = bn_l2[24 + j];
            y = (v[8 + j] - m) * (g * rsqrtf(va + EPS)) + b;
            sv = y / (1.f + expf(-y));
            z0 += w_wl[8 + j] * sv;
            z1 += w_wl[24 + j] * sv;
        }
        lw0s[tid] = 1.f / (1.f + expf(z1 - z0));
    }
    __syncthreads();
    float lw0 = lw0s[pos], lw1 = 1.f - lw0;
    for (int ci = chunk * 64; ci < chunk * 64 + 64; ++ci) {
        long idx = (long)ci * 4096 + p;
        fused[(long)n * 256 * 4096 + idx] = i1[idx] * lw0 + i2[idx] * lw1;
    }
}

// ---------------- prep kernels ----------------
__global__ __launch_bounds__(256) void prep_w_kernel(
    const float* __restrict__ w_conv, const float* __restrict__ w_up,
    const float* __restrict__ w_enc,
    u16* __restrict__ wT, u16* __restrict__ wupT, u16* __restrict__ wencT)
{
    int gid = blockIdx.x * 256 + threadIdx.x;
    if (gid < 589824) {             // wT[t][co][ci] = w_conv[co][ci][t]
        int t = gid >> 16;
        int co = (gid >> 8) & 255;
        int ci = gid & 255;
        wT[gid] = f2bf(w_conv[(co * 256 + ci) * 9 + t]);
    }
    if (gid < 131072) wupT[gid] = f2bf(w_up[gid]);
    if (gid < 73728) {              // wencT[t][co<64][ci] (zeros co>=36)
        int t = gid >> 13;
        int co = (gid >> 7) & 63;
        int ci = gid & 127;
        wencT[gid] = (co < 36) ? f2bf(w_enc[(co * 128 + ci) * 9 + t]) : (u16)0;
    }
}

__global__ void prep_bn_kernel(const float* __restrict__ bn_conv,
                               const float* __restrict__ b_up, float* __restrict__ bnp)
{
    int i = threadIdx.x;            // 256
    float g = bn_conv[i], b = bn_conv[256 + i], m = bn_conv[512 + i], v = bn_conv[768 + i];
    float sc = g * rsqrtf(v + EPS);
    bnp[i] = sc;
    bnp[256 + i] = b - m * sc;
    bnp[512 + i] = 1.f;
    bnp[768 + i] = b_up[i];
}

extern "C" void kernel_launch(void* const* d_in, const int* in_sizes, int n_in,
                              void* d_out, int out_size, void* d_ws, size_t ws_size,
                              hipStream_t stream)
{
    const float* input1 = (const float*)d_in[0];
    const float* input2 = (const float*)d_in[1];
    const float* w_down = (const float*)d_in[2];
    const float* b_down = (const float*)d_in[3];
    const float* w_enc  = (const float*)d_in[4];
    const float* b_enc  = (const float*)d_in[5];
    const float* w_up   = (const float*)d_in[6];
    const float* b_up   = (const float*)d_in[7];
    const float* w_l1   = (const float*)d_in[8];
    const float* bn_l1  = (const float*)d_in[9];
    const float* w_l2   = (const float*)d_in[10];
    const float* bn_l2  = (const float*)d_in[11];
    const float* w_wl   = (const float*)d_in[12];
    const float* b_wl   = (const float*)d_in[13];
    const float* w_conv = (const float*)d_in[14];
    const float* bn_conv= (const float*)d_in[15];
    float* out = (float*)d_out;

    // workspace layout (float units). ~108 MB total.
    float* ws     = (float*)d_ws;
    float* ktTf   = ws;                      //   591,872 f : ktT bf16 [n][1156][128]
    float* wencTf = ktTf + 591872;           //    36,864 f : wencT bf16 [9][64][128]
    float* kt2    = wencTf + 36864;          //   294,912 f
    float* maskb  = kt2 + 294912;            //   294,912 f
    float* u      = maskb + 294912;          // 8,388,608 f
    float* hireb  = u + 8388608;             // 8,388,608 f : hires bf16 [ci][p] ; alias fused fp32
    float* btb    = hireb + 8388608;         // 8,388,608 f : hiresT / fusedT bf16
    float* wTf    = btb + 8388608;           //   294,912 f
    float* wupTf  = wTf + 294912;            //    65,536 f
    float* bnp    = wupTf + 65536;           //     1,024 f
    u16* ktT      = (u16*)ktTf;
    u16* wencT    = (u16*)wencTf;
    u16* hires_bf = (u16*)hireb;
    float* fused  = hireb;
    u16* bt       = (u16*)btb;
    u16* wT       = (u16*)wTf;
    u16* wupT     = (u16*)wupTf;

    // prep (independent of data pipeline)
    prep_w_kernel<<<dim3(2304), 256, 0, stream>>>(w_conv, w_up, w_enc, wT, wupT, wencT);
    prep_bn_kernel<<<dim3(1), 256, 0, stream>>>(bn_conv, b_up, bnp);

    // K1: ktT = bf16T(w_down @ input2 + b_down), padded 34x34 grid
    hipMemsetAsync(ktT, 0, 8L * 1156 * 128 * 2, stream);
    down_gemm_kernel<<<dim3(16, 2, 8), 256, 0, stream>>>(w_down, input2, b_down, ktT);
    // K2: kt2 = 9-tap shifted MFMA GEMM
    enc_mfma_kernel<<<dim3(64, 8), 64, 0, stream>>>(wencT, ktT, b_enc, kt2);
    // K3
    mask_softmax_kernel<<<dim3(128), 256, 0, stream>>>(kt2, maskb);
    // K4: CARAFE -> hires bf16 [ci][p]
    carafe_kernel<<<dim3(16384), 256, 0, stream>>>(input2, maskb, hires_bf);
    // K4b: transpose -> hiresT bf16 [p][512]
    transpose_cast_kernel<512, false, false><<<dim3(128, 8), 256, 0, stream>>>(hires_bf, bt);
    // K5: u = w_up @ hiresT + b_up (LDS-staged MFMA)
    mfma_conv_lds_kernel<512, 1, false><<<dim3(32, 2, 8), 256, 0, stream>>>(
        wupT, bt, bnp + 512, bnp + 768, u, 4096L * 512, 256L * 4096, 0);
    // K6: fused blend (fp32, into hires alias)
    fuse_kernel<<<dim3(512), 256, 0, stream>>>(
        input1, u, w_l1, bn_l1, w_l2, bn_l2, w_wl, b_wl, fused);
    // zero fusedT (padded borders), then K6b transpose-cast
    hipMemsetAsync(bt, 0, 8L * 4356 * 256 * 2, stream);
    transpose_cast_kernel<256, true, true><<<dim3(128, 8), 256, 0, stream>>>(fused, bt);
    // K7: final conv (LDS-staged 9-tap MFMA) + BN + SiLU
    mfma_conv_lds_kernel<256, 9, true><<<dim3(32, 2, 8), 256, 0, stream>>>(
        wT, bt, bnp, bnp + 256, out, 4356L * 256, 256L * 4096, 1);
}